// Round 1
// baseline (562.698 us; speedup 1.0000x reference)
//
#include <hip/hip_runtime.h>
#include <math.h>

// Depth collapses to d=0 (x[:, :, 0:1] slicing): conv1d -> w[3]*xi+b,
// scan at d=0 -> hs[0]=BX[0] (A_log unused), y = xi*(delta*sum(B*C)+D).
//
// This version: ONE persistent kernel (512 blocks x 256 thr, guaranteed
// co-resident at __launch_bounds__(256,2) -> 2 blocks/CU) running all 5
// phases with device-scope grid barriers. Removes 4 inter-kernel
// launch/drain gaps and spreads the ssm phase at wave granularity
// (1 px/wave strided across all blocks) instead of 288 clustered blocks.
#define NB   2
#define CM   96      // D_MODEL
#define CI   192     // D_INNER
#define CO   384     // 2*D_INNER
#define HP   24
#define WP   24
#define PX   576
#define DTR  6
#define NDBC 38
#define CSPLIT 8
#define CCH  12      // input channels per conv chunk (96/CSPLIT)
#define NBLK 512
#define NTHR 256
#define NVB  (NB*HP*6*CSPLIT)   // 2304 virtual conv blocks

#define NW_IN (2*CO*CM*9)       // 663552
#define WQB_L (CM*CO*8)
#define WRB_L (CM*CO)
#define WPT_L (CI*CM)
#define PREP_TOT (NW_IN + 2*CI*CM)

__device__ __forceinline__ float siluf(float x){ return x / (1.f + expf(-x)); }
__device__ __forceinline__ float softplusf(float x){ return x > 20.f ? x : log1pf(expf(x)); }
__device__ __forceinline__ unsigned short f2bf(float f){
    unsigned u = __float_as_uint(f);
    return (unsigned short)((u + 0x7fffu + ((u >> 16) & 1u)) >> 16);
}
__device__ __forceinline__ float bflo(unsigned u){ return __uint_as_float(u << 16); }
__device__ __forceinline__ float bfhi(unsigned u){ return __uint_as_float(u & 0xffff0000u); }

// Grid barrier, non-cooperative. All NBLK blocks are resident by
// construction (2 blocks/CU from launch bounds + 4.2KB LDS). 8 sub-counters
// on distinct 64B lines cut same-line atomic serialization; master on its
// own line. Agent-scope atomics + threadfence give cross-XCD visibility
// (release: L2 writeback; acquire: L1/L2 inv).
__device__ __forceinline__ void gsync(unsigned* bar, int slot){
    __syncthreads();
    __threadfence();
    if (threadIdx.x == 0){
        unsigned* sub    = bar + slot*256 + (blockIdx.x & 7)*16;  // 64B apart
        unsigned* master = bar + slot*256 + 128;                  // own line
        unsigned old = __hip_atomic_fetch_add(sub, 1u, __ATOMIC_ACQ_REL, __HIP_MEMORY_SCOPE_AGENT);
        if (old == (unsigned)(NBLK/8 - 1))
            __hip_atomic_fetch_add(master, 1u, __ATOMIC_ACQ_REL, __HIP_MEMORY_SCOPE_AGENT);
        while (__hip_atomic_load(master, __ATOMIC_ACQUIRE, __HIP_MEMORY_SCOPE_AGENT) < 8u)
            __builtin_amdgcn_s_sleep(2);
    }
    __syncthreads();
    __threadfence();
}

// ---- conv phase body: fused rmsnorm + 3x3 conv (pad 1), bf16 weights,
// fp32 accum. One virtual block = (bx in NB*HP, og in 6, cs in CSPLIT).
// LDS: hs[CCH*3*28] rows (16B-aligned bases), scl[CCH*3].
__device__ __forceinline__ void conv_body(
    int vb, const float* __restrict__ x, long nStr, long cStr,
    const float* __restrict__ nw,
    const unsigned short* __restrict__ wQb, const unsigned short* __restrict__ wRb,
    float* __restrict__ acc, float* __restrict__ hs, float* __restrict__ scl)
{
    int bx = vb % (NB*HP);
    int og = (vb / (NB*HP)) % 6;
    int cs = vb / (NB*HP*6);
    int n  = bx / HP, hh = bx % HP;
    int tid = threadIdx.x;
    int c0 = cs*CCH;

    if (tid < CCH*3){
        int c = tid/3, j = tid%3;
        int row = hh + j - 1;
        float s = 0.f;
        if (row >= 0 && row < HP){
            const float4* xp4 = (const float4*)(x + (long)n*nStr + (long)(c0+c)*cStr + row*WP);
            #pragma unroll
            for (int w4 = 0; w4 < WP/4; w4++){
                float4 v = xp4[w4];
                s += v.x*v.x + v.y*v.y + v.z*v.z + v.w*v.w;
            }
            s = rsqrtf(s*(1.0f/WP) + 1e-5f) * nw[c0+c];
        }
        scl[c*3 + j] = s;
    }
    __syncthreads();

    for (int idx = tid; idx < CCH*3*28; idx += NTHR){
        int c = idx/84; int rem = idx%84; int j = rem/28; int wc = rem%28;
        int row = hh + j - 1;
        float v = 0.f;
        if (row >= 0 && row < HP && wc >= 1 && wc <= WP)
            v = x[(long)n*nStr + (long)(c0+c)*cStr + row*WP + (wc-1)] * scl[c*3 + j];
        hs[idx] = v;
    }
    __syncthreads();

    int ol = tid & 63;
    int o  = og*64 + ol;
    int x0 = (tid >> 6) * 6;           // even -> 8B-aligned float2 loads
    float a0[6] = {0,0,0,0,0,0};
    const uint4* wq4 = (const uint4*)wQb;

    for (int c = 0; c < CCH; c++){
        int cg = c0 + c;
        uint4 wq = wq4[cg*CO + o];
        float w0 = bflo(wq.x), w1 = bfhi(wq.x);
        float w2 = bflo(wq.y), w3 = bfhi(wq.y);
        float w4 = bflo(wq.z), w5 = bfhi(wq.z);
        float w6 = bflo(wq.w), w7 = bfhi(wq.w);
        float w8 = bflo((unsigned)wRb[cg*CO + o]);
        const float* h0 = hs + (c*3 + 0)*28 + x0;
        const float* h1 = hs + (c*3 + 1)*28 + x0;
        const float* h2 = hs + (c*3 + 2)*28 + x0;
        float r0v[8], r1v[8], r2v[8];
        #pragma unroll
        for (int i = 0; i < 4; i++){
            float2 p0 = *(const float2*)(h0 + 2*i);
            float2 p1 = *(const float2*)(h1 + 2*i);
            float2 p2 = *(const float2*)(h2 + 2*i);
            r0v[2*i] = p0.x; r0v[2*i+1] = p0.y;
            r1v[2*i] = p1.x; r1v[2*i+1] = p1.y;
            r2v[2*i] = p2.x; r2v[2*i+1] = p2.y;
        }
        #pragma unroll
        for (int p = 0; p < 6; p++){
            a0[p] += w0*r0v[p] + w1*r0v[p+1] + w2*r0v[p+2]
                   + w3*r1v[p] + w4*r1v[p+1] + w5*r1v[p+2]
                   + w6*r2v[p] + w7*r2v[p+1] + w8*r2v[p+2];
        }
    }

    float* ap = acc + ((long)(cs*NB + n)*PX + hh*WP + x0)*CO + o;
    #pragma unroll
    for (int p = 0; p < 6; p++) ap[p*CO] = a0[p];
}

// ---- ssm phase body: one wave owns one pixel. Fully wave-local (no block
// barriers -> safe under wave-divergent assignment). glw = 192-float LDS
// slice private to this wave.
__device__ __forceinline__ void ssm_body(
    int gw, const float* __restrict__ acc,
    const float* __restrict__ c1w, const float* __restrict__ c1b,
    const float* __restrict__ xpw, const float* __restrict__ dtw,
    const float* __restrict__ dtb, const float* __restrict__ Dp,
    const float* __restrict__ wpT,
    const float* __restrict__ xres, long nStrR, long cStrR,
    float* __restrict__ dst, float* __restrict__ glw)
{
    int lane = threadIdx.x & 63;
    int n = gw / PX, px = gw % PX;

    float xi[3], sz[3];
    #pragma unroll
    for (int t = 0; t < 3; t++){
        int c = lane + 64*t;
        float xr = 0.f, zr = 0.f;
        #pragma unroll
        for (int q = 0; q < CSPLIT; q++){
            const float* ap = acc + ((long)(q*NB + n)*PX + px)*CO;
            xr += ap[c]; zr += ap[CI + c];
        }
        xi[t] = siluf(xr*c1w[c*4 + 3] + c1b[c]);
        sz[t] = siluf(zr);
    }

    float dbc[NDBC];
    #pragma unroll
    for (int j = 0; j < NDBC; j++){
        float s = 0.f;
        #pragma unroll
        for (int t = 0; t < 3; t++) s += xi[t]*xpw[j*CI + lane + 64*t];
        dbc[j] = s;
    }
    #pragma unroll
    for (int step = 1; step < 64; step <<= 1){
        #pragma unroll
        for (int j = 0; j < NDBC; j++) dbc[j] += __shfl_xor(dbc[j], step, 64);
    }
    float BC = 0.f;
    #pragma unroll
    for (int si = 0; si < 16; si++) BC += dbc[6+si]*dbc[22+si];

    #pragma unroll
    for (int t = 0; t < 3; t++){
        int c = lane + 64*t;
        float dl = dtb[c];
        #pragma unroll
        for (int r = 0; r < DTR; r++) dl += dbc[r]*dtw[c*DTR + r];
        dl = softplusf(dl);
        glw[c] = xi[t]*(dl*BC + Dp[c])*sz[t];
    }
    // wave-local LDS RAW: drain ds_writes before cross-lane reads
    asm volatile("s_waitcnt lgkmcnt(0)" ::: "memory");

    #pragma unroll
    for (int mi = 0; mi < 2; mi++){
        int m = mi*64 + lane;
        if (m < CM){
            float s0 = 0.f, s1 = 0.f, s2 = 0.f, s3 = 0.f;
            for (int c = 0; c < CI; c += 4){
                const float4 g4 = *(const float4*)(glw + c);
                s0 += g4.x*wpT[(c+0)*CM + m];
                s1 += g4.y*wpT[(c+1)*CM + m];
                s2 += g4.z*wpT[(c+2)*CM + m];
                s3 += g4.w*wpT[(c+3)*CM + m];
            }
            float s = (s0+s1) + (s2+s3);
            s += xres[(long)n*nStrR + (long)m*cStrR + px];
            dst[(n*CM + m)*PX + px] = s;
        }
    }
}

__global__ __launch_bounds__(NTHR, 2) void mono_k(
    const float* __restrict__ x_in,
    const float* __restrict__ ipw,  const float* __restrict__ c1w,
    const float* __restrict__ c1b,  const float* __restrict__ xpw,
    const float* __restrict__ dtw,  const float* __restrict__ dtb,
    const float* __restrict__ Dp,   const float* __restrict__ opw,
    const float* __restrict__ nw,
    unsigned* __restrict__ bar,
    unsigned short* __restrict__ wQb, unsigned short* __restrict__ wRb,
    float* __restrict__ wpT, float* __restrict__ acc,
    float* __restrict__ x1, float* __restrict__ dout)
{
    // conv: hs = smem[0..1008), scl = smem[1008..1044). ssm: gl = smem[0..768).
    __shared__ float smem[CCH*3*28 + CCH*3];
    const int tid = threadIdx.x;
    const int bid = blockIdx.x;

    // ---- P0: prep (pack in_proj to bf16 [c][o][k], transpose out_proj)
    for (int idx = bid*NTHR + tid; idx < PREP_TOT; idx += NBLK*NTHR){
        if (idx < NW_IN){
            int l = idx / (CO*CM*9);
            int r = idx % (CO*CM*9);
            int o = r / (CM*9);
            int r2 = r % (CM*9);
            int c = r2 / 9;
            int k = r2 % 9;
            unsigned short v = f2bf(ipw[idx]);
            if (k < 8) wQb[(long)l*WQB_L + ((c*CO + o)<<3) + k] = v;
            else       wRb[(long)l*WRB_L + c*CO + o] = v;
        } else {
            int j = idx - NW_IN;
            int l = j / (CI*CM);
            int r = j % (CI*CM);
            int c = r / CM;
            int m = r % CM;
            wpT[l*WPT_L + c*CM + m] = opw[(l*CM + m)*CI + c];
        }
    }
    gsync(bar, 0);

    // ---- layer 0: conv (input: depth-0 slice of x, strides of (2,96,8,24,24))
    for (int vb = bid; vb < NVB; vb += NBLK)
        conv_body(vb, x_in, 96L*8*PX, 8L*PX, nw, wQb, wRb, acc,
                  smem, smem + CCH*3*28);
    gsync(bar, 1);

    // ---- layer 0: ssm, 1 px/wave strided over blocks (all CUs active)
    {
        int wv = tid >> 6;
        int gw = wv*NBLK + bid;
        if (gw < NB*PX)
            ssm_body(gw, acc, c1w, c1b, xpw, dtw, dtb, Dp, wpT,
                     x_in, 96L*8*PX, 8L*PX, x1, smem + wv*CI);
    }
    gsync(bar, 2);

    // ---- layer 1: conv (input x1 packed (2,96,24,24))
    for (int vb = bid; vb < NVB; vb += NBLK)
        conv_body(vb, x1, 96L*PX, (long)PX, nw + CM, wQb + WQB_L, wRb + WRB_L, acc,
                  smem, smem + CCH*3*28);
    gsync(bar, 3);

    // ---- layer 1: ssm (writes final output)
    {
        int wv = tid >> 6;
        int gw = wv*NBLK + bid;
        if (gw < NB*PX)
            ssm_body(gw, acc, c1w + CI*4, c1b + CI, xpw + NDBC*CI, dtw + CI*DTR,
                     dtb + CI, Dp + CI, wpT + WPT_L,
                     x1, 96L*PX, (long)PX, dout, smem + wv*CI);
    }
}

extern "C" void kernel_launch(void* const* d_in, const int* in_sizes, int n_in,
                              void* d_out, int out_size, void* d_ws, size_t ws_size,
                              hipStream_t stream) {
    const float* x_in = (const float*)d_in[0];   // (2,96,8,24,24)
    const float* ipw  = (const float*)d_in[1];   // (2,384,96,1,3,3)
    const float* c1w  = (const float*)d_in[2];   // (2,192,1,4,1,1)
    const float* c1b  = (const float*)d_in[3];   // (2,192)
    const float* xpw  = (const float*)d_in[4];   // (2,38,192)
    const float* dtw  = (const float*)d_in[5];   // (2,192,6)
    const float* dtb  = (const float*)d_in[6];   // (2,192)
    // d_in[7] = A_log: unused at depth 0 (multiplies h[-1]=0)
    const float* Dp   = (const float*)d_in[8];   // (2,192)
    const float* opw  = (const float*)d_in[9];   // (2,96,192)
    const float* nw   = (const float*)d_in[10];  // (2,1,96,1,1,1)

    char* ws = (char*)d_ws;
    unsigned* bar = (unsigned*)ws;                          // 4096 B barrier area
    unsigned short* wQb = (unsigned short*)(ws + 4096);     // 2*294912 ush
    unsigned short* wRb = wQb + 2*WQB_L;                    // 2*36864 ush
    float* wpT = (float*)(wRb + 2*WRB_L);                   // 2*18432 f
    float* acc = wpT + 2*WPT_L;                             // 8*2*576*384 f
    float* x1  = acc + (long)CSPLIT*NB*PX*CO;               // 110592 f

    // ws is re-poisoned between iterations: barrier counters must be zeroed
    // inside the captured sequence every launch.
    hipMemsetAsync(bar, 0, 4096, stream);

    mono_k<<<NBLK, NTHR, 0, stream>>>(
        x_in, ipw, c1w, c1b, xpw, dtw, dtb, Dp, opw, nw,
        bar, wQb, wRb, wpT, acc, x1, (float*)d_out);
}

// Round 2
// 172.857 us; speedup vs baseline: 3.2553x; 3.2553x over previous
//
#include <hip/hip_runtime.h>
#include <math.h>

// Depth collapses to d=0 (x[:, :, 0:1] slicing): conv1d -> w[3]*xi+b,
// scan at d=0 -> hs[0]=BX[0] (A_log unused), y = xi*(delta*sum(B*C)+D).
//
// Multi-kernel structure (known-good @162us) with CSPLIT 8->2:
//  - acc partial buffer 14.2MB -> 3.5MB per layer (4x less HBM roundtrip)
//  - ssm q-loop 8 -> 2 deep
//  - conv grid (48,6,2)=576 blocks, 48 input ch per block, LDS 16.7KB
//  - ssm uses wave-local epilogue (verified in mono round), no block barrier
#define NB   2
#define CM   96      // D_MODEL
#define CI   192     // D_INNER
#define CO   384     // 2*D_INNER
#define HP   24
#define WP   24
#define PX   576
#define DTR  6
#define NDBC 38
#define CSPLIT 2
#define CCH  48      // input channels per conv chunk (96/CSPLIT)

__device__ __forceinline__ float siluf(float x){ return x / (1.f + expf(-x)); }
__device__ __forceinline__ float softplusf(float x){ return x > 20.f ? x : log1pf(expf(x)); }
__device__ __forceinline__ unsigned short f2bf(float f){
    unsigned u = __float_as_uint(f);
    return (unsigned short)((u + 0x7fffu + ((u >> 16) & 1u)) >> 16);
}
__device__ __forceinline__ float bflo(unsigned u){ return __uint_as_float(u << 16); }
__device__ __forceinline__ float bfhi(unsigned u){ return __uint_as_float(u & 0xffff0000u); }

// ---- prep: pack in_proj weights to bf16: wQb[l][c][o][k0..7] (ushort8 = uint4)
//            + wRb[l][c][o] (tap 8), and transpose out_proj -> wpT[l][c][m] fp32
#define NW_IN (2*CO*CM*9)      // 663552
#define WQB_L (CM*CO*8)        // ushorts per layer
#define WRB_L (CM*CO)
#define WPT_L (CI*CM)
__global__ void prep_k(const float* __restrict__ ipw, const float* __restrict__ opw,
                       unsigned short* __restrict__ wQb, unsigned short* __restrict__ wRb,
                       float* __restrict__ wpT){
    int idx = blockIdx.x*256 + threadIdx.x;
    if (idx < NW_IN){
        int l = idx / (CO*CM*9);
        int r = idx % (CO*CM*9);
        int o = r / (CM*9);
        int r2 = r % (CM*9);
        int c = r2 / 9;
        int k = r2 % 9;
        unsigned short v = f2bf(ipw[idx]);
        if (k < 8) wQb[(long)l*WQB_L + ((c*CO + o)<<3) + k] = v;
        else       wRb[(long)l*WRB_L + c*CO + o] = v;
    } else {
        int j = idx - NW_IN;
        if (j < 2*CI*CM){
            int l = j / (CI*CM);
            int r = j % (CI*CM);
            int c = r / CM;
            int m = r % CM;
            wpT[l*WPT_L + c*CM + m] = opw[(l*CM + m)*CI + c];
        }
    }
}

// ---- conv: fused rmsnorm + 3x3 conv (pad 1), bf16 weights, fp32 accum.
// grid (NB*HP, 6 o-groups, CSPLIT c-chunks), block 256 (4 waves x 6-px strips).
// acc layout: [cs][n][px][o]
__global__ __launch_bounds__(256) void conv_k(
    const float* __restrict__ x, long nStr, long cStr,
    const float* __restrict__ nw,
    const unsigned short* __restrict__ wQb, const unsigned short* __restrict__ wRb,
    float* __restrict__ acc)
{
    __shared__ float hs[CCH][3][28];   // 28-wide rows: every (c,j) row base 16B-aligned
    __shared__ float scl[CCH][3];
    int bx = blockIdx.x;
    int og = blockIdx.y;
    int cs = blockIdx.z;
    int n  = bx / HP, hh = bx % HP;
    int tid = threadIdx.x;
    int c0 = cs*CCH;

    if (tid < CCH*3){
        int c = tid/3, j = tid%3;
        int row = hh + j - 1;
        float s = 0.f;
        if (row >= 0 && row < HP){
            const float4* xp4 = (const float4*)(x + (long)n*nStr + (long)(c0+c)*cStr + row*WP);
            #pragma unroll
            for (int w4 = 0; w4 < WP/4; w4++){
                float4 v = xp4[w4];
                s += v.x*v.x + v.y*v.y + v.z*v.z + v.w*v.w;
            }
            s = rsqrtf(s*(1.0f/WP) + 1e-5f) * nw[c0+c];
        }
        scl[c][j] = s;
    }
    __syncthreads();

    for (int idx = tid; idx < CCH*3*28; idx += 256){
        int c = idx/84; int rem = idx%84; int j = rem/28; int wc = rem%28;
        int row = hh + j - 1;
        float v = 0.f;
        if (row >= 0 && row < HP && wc >= 1 && wc <= WP)
            v = x[(long)n*nStr + (long)(c0+c)*cStr + row*WP + (wc-1)] * scl[c][j];
        hs[c][j][wc] = v;
    }
    __syncthreads();

    int ol = tid & 63;
    int o  = og*64 + ol;
    int x0 = (tid >> 6) * 6;           // even -> 8B-aligned float2 loads
    float a0[6] = {0,0,0,0,0,0};
    const uint4* wq4 = (const uint4*)wQb;

    for (int c = 0; c < CCH; c++){
        int cg = c0 + c;
        uint4 wv = wq4[cg*CO + o];
        float w0 = bflo(wv.x), w1 = bfhi(wv.x);
        float w2 = bflo(wv.y), w3 = bfhi(wv.y);
        float w4 = bflo(wv.z), w5 = bfhi(wv.z);
        float w6 = bflo(wv.w), w7 = bfhi(wv.w);
        float w8 = bflo((unsigned)wRb[cg*CO + o]);
        float r0v[8], r1v[8], r2v[8];
        #pragma unroll
        for (int i = 0; i < 4; i++){
            float2 p0 = *(const float2*)(&hs[c][0][x0] + 2*i);
            float2 p1 = *(const float2*)(&hs[c][1][x0] + 2*i);
            float2 p2 = *(const float2*)(&hs[c][2][x0] + 2*i);
            r0v[2*i] = p0.x; r0v[2*i+1] = p0.y;
            r1v[2*i] = p1.x; r1v[2*i+1] = p1.y;
            r2v[2*i] = p2.x; r2v[2*i+1] = p2.y;
        }
        #pragma unroll
        for (int p = 0; p < 6; p++){
            a0[p] += w0*r0v[p] + w1*r0v[p+1] + w2*r0v[p+2]
                   + w3*r1v[p] + w4*r1v[p+1] + w5*r1v[p+2]
                   + w6*r2v[p] + w7*r2v[p+1] + w8*r2v[p+2];
        }
    }

    float* ap = acc + ((long)(cs*NB + n)*PX + hh*WP + x0)*CO + o;
    #pragma unroll
    for (int p = 0; p < 6; p++) ap[p*CO] = a0[p];
}

// ---- ssm: sum partials -> conv1d tap + SiLU gates -> x_proj/dt/BC -> gate ->
//           out_proj + residual. Wave-local: 1 pixel per wave, no block barrier.
//           block 256 = 4 waves = 4 pixels; grid NB*PX/4.
__global__ __launch_bounds__(256) void ssm_k(
    const float* __restrict__ acc,
    const float* __restrict__ c1w, const float* __restrict__ c1b,
    const float* __restrict__ xpw, const float* __restrict__ dtw,
    const float* __restrict__ dtb, const float* __restrict__ Dp,
    const float* __restrict__ wpT,
    const float* __restrict__ xres, long nStrR, long cStrR,
    float* __restrict__ dst)
{
    __shared__ float gl[4][CI];
    int wave = threadIdx.x >> 6, lane = threadIdx.x & 63;
    int p  = blockIdx.x*4 + wave;
    int n  = p / PX, px = p % PX;
    float* glw = gl[wave];

    float xi[3], sz[3];
    #pragma unroll
    for (int t = 0; t < 3; t++){
        int c = lane + 64*t;
        float xr = 0.f, zr = 0.f;
        #pragma unroll
        for (int q = 0; q < CSPLIT; q++){
            const float* ap = acc + ((long)(q*NB + n)*PX + px)*CO;
            xr += ap[c]; zr += ap[CI + c];
        }
        xi[t] = siluf(xr*c1w[c*4 + 3] + c1b[c]);
        sz[t] = siluf(zr);
    }

    float dbc[NDBC];
    #pragma unroll
    for (int j = 0; j < NDBC; j++){
        float s = 0.f;
        #pragma unroll
        for (int t = 0; t < 3; t++) s += xi[t]*xpw[j*CI + lane + 64*t];
        dbc[j] = s;
    }
    #pragma unroll
    for (int step = 1; step < 64; step <<= 1){
        #pragma unroll
        for (int j = 0; j < NDBC; j++) dbc[j] += __shfl_xor(dbc[j], step, 64);
    }
    float BC = 0.f;
    #pragma unroll
    for (int si = 0; si < 16; si++) BC += dbc[6+si]*dbc[22+si];

    #pragma unroll
    for (int t = 0; t < 3; t++){
        int c = lane + 64*t;
        float dl = dtb[c];
        #pragma unroll
        for (int r = 0; r < DTR; r++) dl += dbc[r]*dtw[c*DTR + r];
        dl = softplusf(dl);
        glw[c] = xi[t]*(dl*BC + Dp[c])*sz[t];
    }
    // wave-local LDS RAW: drain ds_writes before cross-lane reads
    asm volatile("s_waitcnt lgkmcnt(0)" ::: "memory");

    #pragma unroll
    for (int mi = 0; mi < 2; mi++){
        int m = mi*64 + lane;
        if (m < CM){
            float s0 = 0.f, s1 = 0.f, s2 = 0.f, s3 = 0.f;
            for (int c = 0; c < CI; c += 4){
                const float4 g4 = *(const float4*)(glw + c);
                s0 += g4.x*wpT[(c+0)*CM + m];
                s1 += g4.y*wpT[(c+1)*CM + m];
                s2 += g4.z*wpT[(c+2)*CM + m];
                s3 += g4.w*wpT[(c+3)*CM + m];
            }
            float s = (s0+s1) + (s2+s3);
            s += xres[(long)n*nStrR + (long)m*cStrR + px];
            dst[(n*CM + m)*PX + px] = s;
        }
    }
}

extern "C" void kernel_launch(void* const* d_in, const int* in_sizes, int n_in,
                              void* d_out, int out_size, void* d_ws, size_t ws_size,
                              hipStream_t stream) {
    const float* x_in = (const float*)d_in[0];   // (2,96,8,24,24)
    const float* ipw  = (const float*)d_in[1];   // (2,384,96,1,3,3)
    const float* c1w  = (const float*)d_in[2];   // (2,192,1,4,1,1)
    const float* c1b  = (const float*)d_in[3];   // (2,192)
    const float* xpw  = (const float*)d_in[4];   // (2,38,192)
    const float* dtw  = (const float*)d_in[5];   // (2,192,6)
    const float* dtb  = (const float*)d_in[6];   // (2,192)
    // d_in[7] = A_log: unused at depth 0 (multiplies h[-1]=0)
    const float* Dp   = (const float*)d_in[8];   // (2,192)
    const float* opw  = (const float*)d_in[9];   // (2,96,192)
    const float* nw   = (const float*)d_in[10];  // (2,1,96,1,1,1)

    char* ws = (char*)d_ws;
    unsigned short* wQb = (unsigned short*)ws;              // 2*294912 ush = 1179648 B
    unsigned short* wRb = wQb + 2*WQB_L;                    // 2*36864 ush  = 147456 B
    float* wpT = (float*)(wRb + 2*WRB_L);                   // 2*18432 f    = 147456 B
    float* acc = wpT + 2*WPT_L;                             // 2*2*576*384 f = 3538944 B
    float* x1  = acc + (long)CSPLIT*NB*PX*CO;               // 110592 f

    prep_k<<<(NW_IN + 2*CI*CM + 255)/256, 256, 0, stream>>>(ipw, opw, wQb, wRb, wpT);

    // ---- layer 0 (input: depth-0 slice of x, strides of (2,96,8,24,24))
    conv_k<<<dim3(NB*HP, 6, CSPLIT), 256, 0, stream>>>(
        x_in, 96L*8*PX, 8L*PX, nw, wQb, wRb, acc);
    ssm_k<<<NB*PX/4, 256, 0, stream>>>(
        acc, c1w, c1b, xpw, dtw, dtb, Dp, wpT,
        x_in, 96L*8*PX, 8L*PX, x1);

    // ---- layer 1 (input x1 packed (2,96,24,24); writes final output)
    conv_k<<<dim3(NB*HP, 6, CSPLIT), 256, 0, stream>>>(
        x1, 96L*PX, (long)PX, nw + CM, wQb + WQB_L, wRb + WRB_L, acc);
    ssm_k<<<NB*PX/4, 256, 0, stream>>>(
        acc, c1w + CI*4, c1b + CI, xpw + NDBC*CI, dtw + CI*DTR, dtb + CI, Dp + CI, wpT + WPT_L,
        x1, 96L*PX, (long)PX, (float*)d_out);
}